// Round 4
// baseline (255.456 us; speedup 1.0000x reference)
//
#include <hip/hip_runtime.h>
#include <math.h>

// Problem constants: B=8, C=64 (in), OC=64 (out), H=W=128, K=3x3=9, PAD=1.
#define Hn 128
#define Wn 128
#define HW 16384
#define NPIX 131072
#define EPSv 1e-5f

// ws layout (floats)
#define XT_OFF   0            // x_t bf16 channels-last [b][y][x][c]: 8388608 shorts = 4194304 floats
#define OFF_OFF  4194304      // 8*18*16384 = 2359296
#define MASK_OFF 6553600      // 8*9*16384  = 1179648
#define WBTA_OFF 7733248      // 20480 shorts = 10240 floats
#define WBTB_OFF 7743488      // 40960 shorts = 20480 floats
#define STAT_OFF 7763968      // 128 (sum[64], sumsq[64])   -> total 7764096 floats = 31.1 MB

// R14 (this round): R13's launch_bounds(256,8) crushed VGPRs to 32 ->
// serialized corner loads + scratch spills (FETCH/WRITE +4MB each, VALUBusy
// 32->29%, dur 85->96 despite occupancy 39->69%). Keep the 2048-block
// 16px/wave split but relax to launch_bounds(256,6) (<=85 VGPR): restores
// the pipelined 4-loads-in-flight schedule AND keeps ~6 waves/SIMD.

typedef short s16x8 __attribute__((ext_vector_type(8)));
typedef unsigned short u16x4 __attribute__((ext_vector_type(4)));
typedef float f32x4 __attribute__((ext_vector_type(4)));
typedef unsigned int u32x4 __attribute__((ext_vector_type(4)));

__device__ __forceinline__ unsigned short f2bf(float f) {
  unsigned u = __float_as_uint(f);
  return (unsigned short)((u + 0x7fffu + ((u >> 16) & 1u)) >> 16);  // RNE
}
__device__ __forceinline__ float bf2f(unsigned short s) {
  return __uint_as_float((unsigned)s << 16);
}
__device__ __forceinline__ unsigned cvt_pk_bf16(float lo, float hi) {
  unsigned r;
  asm("v_cvt_pk_bf16_f32 %0, %1, %2" : "=v"(r) : "v"(lo), "v"(hi));
  return r;
}

// ---------------- prep: pack weights into MFMA operand order; zero stat ----------------
__global__ __launch_bounds__(256) void prep_kernel(
    const float* __restrict__ off_w, const float* __restrict__ mod_w,
    const float* __restrict__ w, unsigned short* __restrict__ wbtA,
    unsigned short* __restrict__ wbtB, float* __restrict__ stat) {
  int i = blockIdx.x * 256 + threadIdx.x;
  if (i < 128) stat[i] = 0.f;
  if (i < 20480) {
    // wbtA: A-operand (weights as rows) for convA.
    int e = i & 31, oc = (i >> 5) & 31, it = i >> 10;
    int tp = it % 5, chunk = it / 5;
    int tap = tp * 2 + (e >> 4);
    int c = (chunk << 4) + (e & 15);
    float v = 0.f;
    if (tap < 9) {
      if (oc < 18) v = off_w[(oc * 64 + c) * 9 + tap];
      else if (oc < 27) v = mod_w[((oc - 18) * 64 + c) * 9 + tap];
    }
    wbtA[i] = f2bf(v);
  } else if (i < 20480 + 40960) {
    // wbtB: B-operand fragments for deform.
    // index = ((it*4 + nt)*64 + lane)*8 + j
    // value = w[oc = nt*16 + (lane&15)][c][tap], where
    //   tap = (it%5)*2 + (lane>>5), c = (it/5)*16 + ((lane>>4)&1)*8 + j
    int j = i - 20480;
    int j3 = j & 7;
    int l = (j >> 3) & 63;
    int nt = (j >> 9) & 3;
    int it = j >> 11;
    int tp = it % 5, chunk = it / 5;
    int tap = tp * 2 + (l >> 5);
    int c = (chunk << 4) + (((l >> 4) & 1) << 3) + j3;
    int oc = (nt << 4) + (l & 15);
    float v = (tap < 9) ? w[(oc * 64 + c) * 9 + tap] : 0.f;
    wbtB[j] = f2bf(v);
  }
}

// ---------------- xform: x (NCHW fp32) -> x_t (NHWC bf16) ----------------
__global__ __launch_bounds__(256) void xform_kernel(
    const float* __restrict__ x, unsigned short* __restrict__ xt) {
  int blk = blockIdx.x;                       // 512 blocks
  int b = blk & 7;
  int hw = ((blk >> 3) << 8) + threadIdx.x;   // 0..16383
  const float* xb = x + ((size_t)(b << 6) << 14) + hw;
  unsigned short* o = xt + (((size_t)(b << 14)) + hw) * 64;
#pragma unroll
  for (int g = 0; g < 8; ++g) {
    float v[8];
#pragma unroll
    for (int j = 0; j < 8; ++j) v[j] = xb[(size_t)((g << 3) + j) << 14];
    s16x8 pk;
#pragma unroll
    for (int j = 0; j < 8; ++j) pk[j] = (short)f2bf(v[j]);
    *(s16x8*)(o + (g << 3)) = pk;
  }
}

// ---------------- kernel A: offset+mask conv, 16 px/wave, grid 2048 ----------------
__global__ __launch_bounds__(256, 6) void convA_mfma_kernel(
    const unsigned short* __restrict__ xt, const unsigned short* __restrict__ wbtA,
    const float* __restrict__ off_b, const float* __restrict__ mod_b,
    float* __restrict__ off_out, float* __restrict__ mask_out) {
  int t = threadIdx.x;
  int bx = blockIdx.x;                  // 2048 = 2 half x 8 b x 128 h
  int half = bx & 1, b = (bx >> 1) & 7, h = bx >> 4;
  int ln = t & 15, quad = (t >> 4) & 3, wv = t >> 6;
  int p0 = (half << 6) + (wv << 4) + ln;
  int s_ = quad >> 1, cj = (quad & 1) << 3;

  f32x4 acc[2];
#pragma unroll
  for (int mt = 0; mt < 2; ++mt) acc[mt] = (f32x4){0.f, 0.f, 0.f, 0.f};

  const unsigned short* xtb = xt + ((size_t)(b << 14)) * 64;

#pragma unroll 5
  for (int it = 0; it < 20; ++it) {
    int chunk = it / 5, tp = it - chunk * 5;
    int tap = tp * 2 + s_;
    s16x8 B0 = (s16x8){0, 0, 0, 0, 0, 0, 0, 0};
    if (tap < 9) {
      int gy = h + tap / 3 - 1;
      if (gy >= 0 && gy < Hn) {
        const unsigned short* rowp = xtb + ((size_t)(gy << 7)) * 64 + (chunk << 4) + cj;
        int gx0 = p0 + tap % 3 - 1;
        if (gx0 >= 0 && gx0 < Wn) B0 = *(const s16x8*)(rowp + (gx0 << 6));
      }
    }
#pragma unroll
    for (int mt = 0; mt < 2; ++mt) {
      s16x8 A = *(const s16x8*)(wbtA + (size_t)((it << 5) + (mt << 4) + ln) * 32 + (quad << 3));
      acc[mt] = __builtin_amdgcn_mfma_f32_16x16x32_bf16(A, B0, acc[mt], 0, 0, 0);
    }
  }

  int hw = h << 7;
#pragma unroll
  for (int mt = 0; mt < 2; ++mt)
#pragma unroll
    for (int r = 0; r < 4; ++r) {
      int oc = (mt << 4) + (quad << 2) + r;
      int px = p0;  // D col = lane&15 = ln -> px; row = quad*4+r -> oc
      float val = acc[mt][r];
      if (oc < 18) {
        off_out[(((size_t)b * 18 + oc) << 14) + hw + px] = val + off_b[oc];
      } else if (oc < 27) {
        float z = val + mod_b[oc - 18];
        mask_out[(((size_t)b * 9 + (oc - 18)) << 14) + hw + px] = 2.f / (1.f + expf(-z));
      }
    }
}

// ---------------- kernel B: deform conv, 16 px/wave, grid 2048, launch_bounds(256,6) ----------------
__global__ __launch_bounds__(256, 6) void deform_mfma_kernel(
    const unsigned short* __restrict__ xt, const float* __restrict__ off,
    const float* __restrict__ mask, const unsigned short* __restrict__ wbtB,
    const float* __restrict__ bias, float* __restrict__ y) {
  __shared__ unsigned short geow[9 * 64 * 4];  // 4608 B: w00,w01,w10,w11 bf16 (mask folded)
  __shared__ unsigned short geoi[9 * 64];      // 1152 B: ibase = rbase*128+cbase
  int t = threadIdx.x;
  int bx = blockIdx.x;                  // 2048 = 2 half x 8 b x 128 h
  int half = bx & 1, b = (bx >> 1) & 7, h = bx >> 4;
  int lane = t & 63, wv = t >> 6;
  int l4 = lane & 15;
  int s4 = lane >> 4;        // k-slice 0..3
  int tapS = lane >> 5;      // which tap of the pair
  int chalf = s4 & 1;        // which 8ch half of the 16ch chunk
  int hw = h << 7;
  int pxb = half << 6;

  // ---- prologue: geometry for 64 px x 9 taps, bilinear weight products folded ----
  for (int i = t; i < 576; i += 256) {
    int tap = i >> 6, p2 = i & 63;
    int px = pxb + p2;
    int ob = ((b * 18 + 2 * tap) << 14) + hw + px;
    float dy = off[ob];
    float dx = off[ob + HW];
    float m = mask[((b * 9 + tap) << 14) + hw + px];
    float py = dy + (float)(h + tap / 3 - 1);
    float pxf = dx + (float)(px + tap % 3 - 1);
    float y0f = floorf(py), x0f = floorf(pxf);
    float ly = py - y0f, lx = pxf - x0f;
    int y0 = (int)y0f, x0 = (int)x0f;
    int y1 = y0 + 1, x1 = x0 + 1;
    float fy0 = (y0 >= 0 && y0 < Hn) ? 1.f : 0.f;
    float fy1 = (y1 >= 0 && y1 < Hn) ? 1.f : 0.f;
    float fx0 = (x0 >= 0 && x0 < Wn) ? 1.f : 0.f;
    float fx1 = (x1 >= 0 && x1 < Wn) ? 1.f : 0.f;
    float ax0 = (1.f - lx) * fx0, ax1 = lx * fx1;
    float ay0 = (1.f - ly) * fy0 * m, ay1 = ly * fy1 * m;
    int cy0 = min(max(y0, 0), Hn - 1), cy1 = min(max(y1, 0), Hn - 1);
    int cx0 = min(max(x0, 0), Wn - 1), cx1 = min(max(x1, 0), Wn - 1);
    int cbase = min(cx0, Wn - 2), rbase = min(cy0, Hn - 2);
    float gx0 = (cx0 == cbase ? ax0 : 0.f) + (cx1 == cbase ? ax1 : 0.f);
    float gx1 = (cx0 == cbase + 1 ? ax0 : 0.f) + (cx1 == cbase + 1 ? ax1 : 0.f);
    float gy0 = (cy0 == rbase ? ay0 : 0.f) + (cy1 == rbase ? ay1 : 0.f);
    float gy1 = (cy0 == rbase + 1 ? ay0 : 0.f) + (cy1 == rbase + 1 ? ay1 : 0.f);
    unsigned short* gw = geow + i * 4;
    gw[0] = f2bf(gy0 * gx0);
    gw[1] = f2bf(gy0 * gx1);
    gw[2] = f2bf(gy1 * gx0);
    gw[3] = f2bf(gy1 * gx1);
    geoi[i] = (unsigned short)((rbase << 7) + cbase);
  }
  __syncthreads();

  f32x4 acc[4];  // 4 n-tiles (oc 16 each), 1 m-tile (16 px)
#pragma unroll
  for (int n = 0; n < 4; ++n) acc[n] = (f32x4){0.f, 0.f, 0.f, 0.f};

  const unsigned short* xtb = xt + ((size_t)(b << 14)) * 64;

  for (int tp = 0; tp < 5; ++tp) {
    int tap = tp * 2 + tapS;
    bool live = (tap < 9);
    float w00, w01, w10, w11;
    const unsigned short* cpb;
    if (live) {
      int gidx = (tap << 6) + (wv << 4) + l4;
      u16x4 wq = *(const u16x4*)(geow + gidx * 4);
      unsigned ib = geoi[gidx];
      w00 = bf2f(wq[0]);
      w01 = bf2f(wq[1]);
      w10 = bf2f(wq[2]);
      w11 = bf2f(wq[3]);
      cpb = xtb + (size_t)ib * 64 + (chalf << 3);
    } else {
      cpb = xtb;
      w00 = w01 = w10 = w11 = 0.f;
    }
#pragma unroll
    for (int chunk = 0; chunk < 4; ++chunk) {
      int it = chunk * 5 + tp;
      u32x4 au = (u32x4){0u, 0u, 0u, 0u};
      if (live) {
        const unsigned short* cp = cpb + (chunk << 4);
        s16x8 c00 = *(const s16x8*)(cp);
        s16x8 c01 = *(const s16x8*)(cp + 64);
        s16x8 c10 = *(const s16x8*)(cp + 8192);
        s16x8 c11 = *(const s16x8*)(cp + 8192 + 64);
#pragma unroll
        for (int jj = 0; jj < 4; ++jj) {
          float v0 = w00 * bf2f((unsigned short)c00[2 * jj]) +
                     w01 * bf2f((unsigned short)c01[2 * jj]) +
                     w10 * bf2f((unsigned short)c10[2 * jj]) +
                     w11 * bf2f((unsigned short)c11[2 * jj]);
          float v1 = w00 * bf2f((unsigned short)c00[2 * jj + 1]) +
                     w01 * bf2f((unsigned short)c01[2 * jj + 1]) +
                     w10 * bf2f((unsigned short)c10[2 * jj + 1]) +
                     w11 * bf2f((unsigned short)c11[2 * jj + 1]);
          au[jj] = cvt_pk_bf16(v0, v1);
        }
      }
      s16x8 A = __builtin_bit_cast(s16x8, au);
      const unsigned short* wb = wbtB + (((size_t)it) << 11) + (lane << 3);
#pragma unroll
      for (int n = 0; n < 4; ++n) {
        s16x8 Bf = *(const s16x8*)(wb + (n << 9));
        acc[n] = __builtin_amdgcn_mfma_f32_16x16x32_bf16(A, Bf, acc[n], 0, 0, 0);
      }
    }
  }

  // epilogue: D row = px-in-tile = s4*4+r (float4 over r), col = oc-in-tile = l4
  int px0 = pxb + (wv << 4) + (s4 << 2);
#pragma unroll
  for (int n = 0; n < 4; ++n) {
    int oc = (n << 4) + l4;
    float bv = bias[oc];
    float4 o;
    o.x = acc[n][0] + bv;
    o.y = acc[n][1] + bv;
    o.z = acc[n][2] + bv;
    o.w = acc[n][3] + bv;
    *(float4*)(y + (((size_t)(b << 6) + oc) << 14) + hw + px0) = o;
  }
}

// ---------------- kernel C: per-channel sum/sumsq (sliced, atomics into stat) ----------------
__global__ __launch_bounds__(256) void stats2_kernel(
    const float* __restrict__ y, float* __restrict__ stat) {
  int bxx = blockIdx.x;            // 1024 = 64 ch x 16 slices
  int c = bxx & 63, sl = bxx >> 6;
  int bb = sl >> 1;
  const float4* yp = (const float4*)(y + (((size_t)bb * 64 + c) << 14) + ((sl & 1) << 13));
  float s = 0.f, ss = 0.f;
  for (int i = threadIdx.x; i < 2048; i += 256) {
    float4 v = yp[i];
    s += v.x + v.y + v.z + v.w;
    ss += v.x * v.x + v.y * v.y + v.z * v.z + v.w * v.w;
  }
#pragma unroll
  for (int o = 32; o > 0; o >>= 1) {
    s += __shfl_xor(s, o);
    ss += __shfl_xor(ss, o);
  }
  __shared__ float shs[4], shss[4];
  int lane = threadIdx.x & 63, wv = threadIdx.x >> 6;
  if (lane == 0) { shs[wv] = s; shss[wv] = ss; }
  __syncthreads();
  if (threadIdx.x == 0) {
    float S = shs[0] + shs[1] + shs[2] + shs[3];
    float SS = shss[0] + shss[1] + shss[2] + shss[3];
    atomicAdd(stat + c, S);
    atomicAdd(stat + 64 + c, SS);
  }
}

// ---------------- kernel D: batchnorm scale/shift + relu, in place ----------------
__global__ __launch_bounds__(256) void bnrelu_kernel(
    float* __restrict__ y, const float* __restrict__ stat,
    const float* __restrict__ gamma, const float* __restrict__ beta) {
  float4* y4 = (float4*)y;
  for (int i = blockIdx.x * 256 + threadIdx.x; i < 2097152; i += gridDim.x * 256) {
    int c = (i >> 12) & 63;
    float mean = stat[c] * (1.f / (float)NPIX);
    float var = stat[64 + c] * (1.f / (float)NPIX) - mean * mean;
    float r = rsqrtf(var + EPSv);
    float g = gamma[c] * r;
    float bt = beta[c] - mean * g;
    float4 v = y4[i];
    v.x = fmaxf(v.x * g + bt, 0.f);
    v.y = fmaxf(v.y * g + bt, 0.f);
    v.z = fmaxf(v.z * g + bt, 0.f);
    v.w = fmaxf(v.w * g + bt, 0.f);
    y4[i] = v;
  }
}

extern "C" void kernel_launch(void* const* d_in, const int* in_sizes, int n_in,
                              void* d_out, int out_size, void* d_ws, size_t ws_size,
                              hipStream_t stream) {
  const float* x     = (const float*)d_in[0];
  const float* off_w = (const float*)d_in[1];
  const float* off_b = (const float*)d_in[2];
  const float* mod_w = (const float*)d_in[3];
  const float* mod_b = (const float*)d_in[4];
  const float* w     = (const float*)d_in[5];
  const float* b     = (const float*)d_in[6];
  const float* gamma = (const float*)d_in[7];
  const float* beta  = (const float*)d_in[8];
  float* out = (float*)d_out;
  float* ws  = (float*)d_ws;

  unsigned short* xt  = (unsigned short*)(ws + XT_OFF);
  float* offo  = ws + OFF_OFF;
  float* masko = ws + MASK_OFF;
  unsigned short* wbtA = (unsigned short*)(ws + WBTA_OFF);
  unsigned short* wbtB = (unsigned short*)(ws + WBTB_OFF);
  float* stat  = ws + STAT_OFF;

  prep_kernel<<<240, 256, 0, stream>>>(off_w, mod_w, w, wbtA, wbtB, stat);
  xform_kernel<<<512, 256, 0, stream>>>(x, xt);
  convA_mfma_kernel<<<2048, 256, 0, stream>>>(xt, wbtA, off_b, mod_b, offo, masko);
  deform_mfma_kernel<<<2048, 256, 0, stream>>>(xt, offo, masko, wbtB, b, out);
  stats2_kernel<<<1024, 256, 0, stream>>>(out, stat);
  bnrelu_kernel<<<8192, 256, 0, stream>>>(out, stat, gamma, beta);
}

// Round 5
// 249.545 us; speedup vs baseline: 1.0237x; 1.0237x over previous
//
#include <hip/hip_runtime.h>
#include <math.h>

// Problem constants: B=8, C=64 (in), OC=64 (out), H=W=128, K=3x3=9, PAD=1.
#define Hn 128
#define Wn 128
#define HW 16384
#define NPIX 131072
#define EPSv 1e-5f

// ws layout (floats)
#define XT_OFF   0            // x_t bf16 channels-last [b][y][x][c]: 8388608 shorts = 4194304 floats
#define OFF_OFF  4194304      // 8*18*16384 = 2359296
#define MASK_OFF 6553600      // 8*9*16384  = 1179648
#define WBTA_OFF 7733248      // 20480 shorts = 10240 floats
#define WBTB_OFF 7743488      // 40960 shorts = 20480 floats
#define STAT_OFF 7763968      // 128 (sum[64], sumsq[64])   -> total 7764096 floats = 31.1 MB

// R15 (this round): MLP, not occupancy. Evidence: dur tracks in-flight
// gather loads per SIMD (R12 MLP~25=85us, R14 MLP~18=103us, R13 spill=96us).
// Per (px,tap) all 4 chunks' corner addresses are cpb+chunk*32B -> issue all
// 16 corner loads per tp up front, consume chunk-by-chunk (in-order vmcnt
// keeps chunk3 loads in flight during chunk0 compute). 16 loads/wave x 4
// waves/SIMD ~ MLP 64 (2.5x R12). launch_bounds(256,4) so the allocator
// does NOT squeeze (R14's 36-VGPR serialization). Branchless dead-tap path
// (zero weights -> A=0). s_setprio(1) around MFMA quartet (independent
// waves = attn-like regime where T5 measured +4-7%). convA reverted to the
// proven R12 form (1024 blocks, 2 n-tiles, bounds(256,4)).

typedef short s16x8 __attribute__((ext_vector_type(8)));
typedef unsigned short u16x4 __attribute__((ext_vector_type(4)));
typedef float f32x4 __attribute__((ext_vector_type(4)));
typedef unsigned int u32x4 __attribute__((ext_vector_type(4)));

__device__ __forceinline__ unsigned short f2bf(float f) {
  unsigned u = __float_as_uint(f);
  return (unsigned short)((u + 0x7fffu + ((u >> 16) & 1u)) >> 16);  // RNE
}
__device__ __forceinline__ float bf2f(unsigned short s) {
  return __uint_as_float((unsigned)s << 16);
}
__device__ __forceinline__ unsigned cvt_pk_bf16(float lo, float hi) {
  unsigned r;
  asm("v_cvt_pk_bf16_f32 %0, %1, %2" : "=v"(r) : "v"(lo), "v"(hi));
  return r;
}

// ---------------- prep: pack weights into MFMA operand order; zero stat ----------------
__global__ __launch_bounds__(256) void prep_kernel(
    const float* __restrict__ off_w, const float* __restrict__ mod_w,
    const float* __restrict__ w, unsigned short* __restrict__ wbtA,
    unsigned short* __restrict__ wbtB, float* __restrict__ stat) {
  int i = blockIdx.x * 256 + threadIdx.x;
  if (i < 128) stat[i] = 0.f;
  if (i < 20480) {
    // wbtA: A-operand (weights as rows) for convA.
    int e = i & 31, oc = (i >> 5) & 31, it = i >> 10;
    int tp = it % 5, chunk = it / 5;
    int tap = tp * 2 + (e >> 4);
    int c = (chunk << 4) + (e & 15);
    float v = 0.f;
    if (tap < 9) {
      if (oc < 18) v = off_w[(oc * 64 + c) * 9 + tap];
      else if (oc < 27) v = mod_w[((oc - 18) * 64 + c) * 9 + tap];
    }
    wbtA[i] = f2bf(v);
  } else if (i < 20480 + 40960) {
    // wbtB: B-operand fragments for deform.
    // index = ((it*4 + nt)*64 + lane)*8 + j
    // value = w[oc = nt*16 + (lane&15)][c][tap], where
    //   tap = (it%5)*2 + (lane>>5), c = (it/5)*16 + ((lane>>4)&1)*8 + j
    int j = i - 20480;
    int j3 = j & 7;
    int l = (j >> 3) & 63;
    int nt = (j >> 9) & 3;
    int it = j >> 11;
    int tp = it % 5, chunk = it / 5;
    int tap = tp * 2 + (l >> 5);
    int c = (chunk << 4) + (((l >> 4) & 1) << 3) + j3;
    int oc = (nt << 4) + (l & 15);
    float v = (tap < 9) ? w[(oc * 64 + c) * 9 + tap] : 0.f;
    wbtB[j] = f2bf(v);
  }
}

// ---------------- xform: x (NCHW fp32) -> x_t (NHWC bf16) ----------------
__global__ __launch_bounds__(256) void xform_kernel(
    const float* __restrict__ x, unsigned short* __restrict__ xt) {
  int blk = blockIdx.x;                       // 512 blocks
  int b = blk & 7;
  int hw = ((blk >> 3) << 8) + threadIdx.x;   // 0..16383
  const float* xb = x + ((size_t)(b << 6) << 14) + hw;
  unsigned short* o = xt + (((size_t)(b << 14)) + hw) * 64;
#pragma unroll
  for (int g = 0; g < 8; ++g) {
    float v[8];
#pragma unroll
    for (int j = 0; j < 8; ++j) v[j] = xb[(size_t)((g << 3) + j) << 14];
    s16x8 pk;
#pragma unroll
    for (int j = 0; j < 8; ++j) pk[j] = (short)f2bf(v[j]);
    *(s16x8*)(o + (g << 3)) = pk;
  }
}

// ---------------- kernel A: offset+mask conv (R12 form: 1024 blocks, 32 px/wave) ----------------
__global__ __launch_bounds__(256, 4) void convA_mfma_kernel(
    const unsigned short* __restrict__ xt, const unsigned short* __restrict__ wbtA,
    const float* __restrict__ off_b, const float* __restrict__ mod_b,
    float* __restrict__ off_out, float* __restrict__ mask_out) {
  int t = threadIdx.x;
  int bx = blockIdx.x;
  int b = bx & 7, h = bx >> 3;
  int ln = t & 15, quad = (t >> 4) & 3, wv = t >> 6;
  int p0 = (wv << 5) + ln, p1 = p0 + 16;
  int s_ = quad >> 1, cj = (quad & 1) << 3;

  f32x4 acc[2][2];
#pragma unroll
  for (int mt = 0; mt < 2; ++mt)
#pragma unroll
    for (int nt = 0; nt < 2; ++nt) acc[mt][nt] = (f32x4){0.f, 0.f, 0.f, 0.f};

  const unsigned short* xtb = xt + ((size_t)(b << 14)) * 64;

#pragma unroll 5
  for (int it = 0; it < 20; ++it) {
    int chunk = it / 5, tp = it - chunk * 5;
    int tap = tp * 2 + s_;
    s16x8 B0 = (s16x8){0, 0, 0, 0, 0, 0, 0, 0};
    s16x8 B1 = (s16x8){0, 0, 0, 0, 0, 0, 0, 0};
    if (tap < 9) {
      int gy = h + tap / 3 - 1;
      if (gy >= 0 && gy < Hn) {
        const unsigned short* rowp = xtb + ((size_t)(gy << 7)) * 64 + (chunk << 4) + cj;
        int gx0 = p0 + tap % 3 - 1;
        int gx1 = p1 + tap % 3 - 1;
        if (gx0 >= 0 && gx0 < Wn) B0 = *(const s16x8*)(rowp + (gx0 << 6));
        if (gx1 >= 0 && gx1 < Wn) B1 = *(const s16x8*)(rowp + (gx1 << 6));
      }
    }
#pragma unroll
    for (int mt = 0; mt < 2; ++mt) {
      s16x8 A = *(const s16x8*)(wbtA + (size_t)((it << 5) + (mt << 4) + ln) * 32 + (quad << 3));
      acc[mt][0] = __builtin_amdgcn_mfma_f32_16x16x32_bf16(A, B0, acc[mt][0], 0, 0, 0);
      acc[mt][1] = __builtin_amdgcn_mfma_f32_16x16x32_bf16(A, B1, acc[mt][1], 0, 0, 0);
    }
  }

  int hw = h << 7;
#pragma unroll
  for (int mt = 0; mt < 2; ++mt)
#pragma unroll
    for (int r = 0; r < 4; ++r) {
      int oc = (mt << 4) + (quad << 2) + r;
#pragma unroll
      for (int nt = 0; nt < 2; ++nt) {
        int px = (wv << 5) + (nt << 4) + ln;
        float val = acc[mt][nt][r];
        if (oc < 18) {
          off_out[(((size_t)b * 18 + oc) << 14) + hw + px] = val + off_b[oc];
        } else if (oc < 27) {
          float z = val + mod_b[oc - 18];
          mask_out[(((size_t)b * 9 + (oc - 18)) << 14) + hw + px] = 2.f / (1.f + expf(-z));
        }
      }
    }
}

// ---------------- kernel B: deform conv, 16 px/wave, full-tp prefetch (16 loads in flight) ----------------
__global__ __launch_bounds__(256, 4) void deform_mfma_kernel(
    const unsigned short* __restrict__ xt, const float* __restrict__ off,
    const float* __restrict__ mask, const unsigned short* __restrict__ wbtB,
    const float* __restrict__ bias, float* __restrict__ y) {
  __shared__ unsigned short geow[9 * 64 * 4];  // 4608 B: w00,w01,w10,w11 bf16 (mask folded)
  __shared__ unsigned short geoi[9 * 64];      // 1152 B: ibase = rbase*128+cbase
  int t = threadIdx.x;
  int bx = blockIdx.x;                  // 2048 = 2 half x 8 b x 128 h
  int half = bx & 1, b = (bx >> 1) & 7, h = bx >> 4;
  int lane = t & 63, wv = t >> 6;
  int l4 = lane & 15;
  int s4 = lane >> 4;        // k-slice 0..3
  int tapS = lane >> 5;      // which tap of the pair
  int chalf = s4 & 1;        // which 8ch half of the 16ch chunk
  int hw = h << 7;
  int pxb = half << 6;

  // ---- prologue: geometry for 64 px x 9 taps, bilinear weight products folded ----
  for (int i = t; i < 576; i += 256) {
    int tap = i >> 6, p2 = i & 63;
    int px = pxb + p2;
    int ob = ((b * 18 + 2 * tap) << 14) + hw + px;
    float dy = off[ob];
    float dx = off[ob + HW];
    float m = mask[((b * 9 + tap) << 14) + hw + px];
    float py = dy + (float)(h + tap / 3 - 1);
    float pxf = dx + (float)(px + tap % 3 - 1);
    float y0f = floorf(py), x0f = floorf(pxf);
    float ly = py - y0f, lx = pxf - x0f;
    int y0 = (int)y0f, x0 = (int)x0f;
    int y1 = y0 + 1, x1 = x0 + 1;
    float fy0 = (y0 >= 0 && y0 < Hn) ? 1.f : 0.f;
    float fy1 = (y1 >= 0 && y1 < Hn) ? 1.f : 0.f;
    float fx0 = (x0 >= 0 && x0 < Wn) ? 1.f : 0.f;
    float fx1 = (x1 >= 0 && x1 < Wn) ? 1.f : 0.f;
    float ax0 = (1.f - lx) * fx0, ax1 = lx * fx1;
    float ay0 = (1.f - ly) * fy0 * m, ay1 = ly * fy1 * m;
    int cy0 = min(max(y0, 0), Hn - 1), cy1 = min(max(y1, 0), Hn - 1);
    int cx0 = min(max(x0, 0), Wn - 1), cx1 = min(max(x1, 0), Wn - 1);
    int cbase = min(cx0, Wn - 2), rbase = min(cy0, Hn - 2);
    float gx0 = (cx0 == cbase ? ax0 : 0.f) + (cx1 == cbase ? ax1 : 0.f);
    float gx1 = (cx0 == cbase + 1 ? ax0 : 0.f) + (cx1 == cbase + 1 ? ax1 : 0.f);
    float gy0 = (cy0 == rbase ? ay0 : 0.f) + (cy1 == rbase ? ay1 : 0.f);
    float gy1 = (cy0 == rbase + 1 ? ay0 : 0.f) + (cy1 == rbase + 1 ? ay1 : 0.f);
    unsigned short* gw = geow + i * 4;
    gw[0] = f2bf(gy0 * gx0);
    gw[1] = f2bf(gy0 * gx1);
    gw[2] = f2bf(gy1 * gx0);
    gw[3] = f2bf(gy1 * gx1);
    geoi[i] = (unsigned short)((rbase << 7) + cbase);
  }
  __syncthreads();

  f32x4 acc[4];  // 4 n-tiles (oc 16 each), 1 m-tile (16 px)
#pragma unroll
  for (int n = 0; n < 4; ++n) acc[n] = (f32x4){0.f, 0.f, 0.f, 0.f};

  const unsigned short* xtb = xt + ((size_t)(b << 14)) * 64;

#pragma unroll 1
  for (int tp = 0; tp < 5; ++tp) {
    int tap = tp * 2 + tapS;
    bool live = (tap < 9);
    // geometry: one (px, tap) per lane; dead lanes get zero weights -> A=0 (branchless)
    int gidx = ((live ? tap : 0) << 6) + (wv << 4) + l4;
    u16x4 wq = *(const u16x4*)(geow + gidx * 4);
    unsigned ib = geoi[gidx];
    float w00 = live ? bf2f(wq[0]) : 0.f;
    float w01 = live ? bf2f(wq[1]) : 0.f;
    float w10 = live ? bf2f(wq[2]) : 0.f;
    float w11 = live ? bf2f(wq[3]) : 0.f;
    const unsigned short* cpb = xtb + (size_t)ib * 64 + (chalf << 3);

    // issue ALL 16 corner loads (4 chunks x 4 corners) before any compute
    s16x8 c00[4], c01[4], c10[4], c11[4];
#pragma unroll
    for (int chunk = 0; chunk < 4; ++chunk) {
      const unsigned short* cp = cpb + (chunk << 4);
      c00[chunk] = *(const s16x8*)(cp);
      c01[chunk] = *(const s16x8*)(cp + 64);
      c10[chunk] = *(const s16x8*)(cp + 8192);
      c11[chunk] = *(const s16x8*)(cp + 8192 + 64);
    }

#pragma unroll
    for (int chunk = 0; chunk < 4; ++chunk) {
      int it = chunk * 5 + tp;
      u32x4 au;
#pragma unroll
      for (int jj = 0; jj < 4; ++jj) {
        float v0 = w00 * bf2f((unsigned short)c00[chunk][2 * jj]) +
                   w01 * bf2f((unsigned short)c01[chunk][2 * jj]) +
                   w10 * bf2f((unsigned short)c10[chunk][2 * jj]) +
                   w11 * bf2f((unsigned short)c11[chunk][2 * jj]);
        float v1 = w00 * bf2f((unsigned short)c00[chunk][2 * jj + 1]) +
                   w01 * bf2f((unsigned short)c01[chunk][2 * jj + 1]) +
                   w10 * bf2f((unsigned short)c10[chunk][2 * jj + 1]) +
                   w11 * bf2f((unsigned short)c11[chunk][2 * jj + 1]);
        au[jj] = cvt_pk_bf16(v0, v1);
      }
      s16x8 A = __builtin_bit_cast(s16x8, au);
      const unsigned short* wb = wbtB + (((size_t)it) << 11) + (lane << 3);
      __builtin_amdgcn_s_setprio(1);
#pragma unroll
      for (int n = 0; n < 4; ++n) {
        s16x8 Bf = *(const s16x8*)(wb + (n << 9));
        acc[n] = __builtin_amdgcn_mfma_f32_16x16x32_bf16(A, Bf, acc[n], 0, 0, 0);
      }
      __builtin_amdgcn_s_setprio(0);
    }
  }

  // epilogue: D row = px-in-tile = s4*4+r (float4 over r), col = oc-in-tile = l4
  int px0 = pxb + (wv << 4) + (s4 << 2);
#pragma unroll
  for (int n = 0; n < 4; ++n) {
    int oc = (n << 4) + l4;
    float bv = bias[oc];
    float4 o;
    o.x = acc[n][0] + bv;
    o.y = acc[n][1] + bv;
    o.z = acc[n][2] + bv;
    o.w = acc[n][3] + bv;
    *(float4*)(y + (((size_t)(b << 6) + oc) << 14) + hw + px0) = o;
  }
}

// ---------------- kernel C: per-channel sum/sumsq (sliced, atomics into stat) ----------------
__global__ __launch_bounds__(256) void stats2_kernel(
    const float* __restrict__ y, float* __restrict__ stat) {
  int bxx = blockIdx.x;            // 1024 = 64 ch x 16 slices
  int c = bxx & 63, sl = bxx >> 6;
  int bb = sl >> 1;
  const float4* yp = (const float4*)(y + (((size_t)bb * 64 + c) << 14) + ((sl & 1) << 13));
  float s = 0.f, ss = 0.f;
  for (int i = threadIdx.x; i < 2048; i += 256) {
    float4 v = yp[i];
    s += v.x + v.y + v.z + v.w;
    ss += v.x * v.x + v.y * v.y + v.z * v.z + v.w * v.w;
  }
#pragma unroll
  for (int o = 32; o > 0; o >>= 1) {
    s += __shfl_xor(s, o);
    ss += __shfl_xor(ss, o);
  }
  __shared__ float shs[4], shss[4];
  int lane = threadIdx.x & 63, wv = threadIdx.x >> 6;
  if (lane == 0) { shs[wv] = s; shss[wv] = ss; }
  __syncthreads();
  if (threadIdx.x == 0) {
    float S = shs[0] + shs[1] + shs[2] + shs[3];
    float SS = shss[0] + shss[1] + shss[2] + shss[3];
    atomicAdd(stat + c, S);
    atomicAdd(stat + 64 + c, SS);
  }
}

// ---------------- kernel D: batchnorm scale/shift + relu, in place ----------------
__global__ __launch_bounds__(256) void bnrelu_kernel(
    float* __restrict__ y, const float* __restrict__ stat,
    const float* __restrict__ gamma, const float* __restrict__ beta) {
  float4* y4 = (float4*)y;
  for (int i = blockIdx.x * 256 + threadIdx.x; i < 2097152; i += gridDim.x * 256) {
    int c = (i >> 12) & 63;
    float mean = stat[c] * (1.f / (float)NPIX);
    float var = stat[64 + c] * (1.f / (float)NPIX) - mean * mean;
    float r = rsqrtf(var + EPSv);
    float g = gamma[c] * r;
    float bt = beta[c] - mean * g;
    float4 v = y4[i];
    v.x = fmaxf(v.x * g + bt, 0.f);
    v.y = fmaxf(v.y * g + bt, 0.f);
    v.z = fmaxf(v.z * g + bt, 0.f);
    v.w = fmaxf(v.w * g + bt, 0.f);
    y4[i] = v;
  }
}

extern "C" void kernel_launch(void* const* d_in, const int* in_sizes, int n_in,
                              void* d_out, int out_size, void* d_ws, size_t ws_size,
                              hipStream_t stream) {
  const float* x     = (const float*)d_in[0];
  const float* off_w = (const float*)d_in[1];
  const float* off_b = (const float*)d_in[2];
  const float* mod_w = (const float*)d_in[3];
  const float* mod_b = (const float*)d_in[4];
  const float* w     = (const float*)d_in[5];
  const float* b     = (const float*)d_in[6];
  const float* gamma = (const float*)d_in[7];
  const float* beta  = (const float*)d_in[8];
  float* out = (float*)d_out;
  float* ws  = (float*)d_ws;

  unsigned short* xt  = (unsigned short*)(ws + XT_OFF);
  float* offo  = ws + OFF_OFF;
  float* masko = ws + MASK_OFF;
  unsigned short* wbtA = (unsigned short*)(ws + WBTA_OFF);
  unsigned short* wbtB = (unsigned short*)(ws + WBTB_OFF);
  float* stat  = ws + STAT_OFF;

  prep_kernel<<<240, 256, 0, stream>>>(off_w, mod_w, w, wbtA, wbtB, stat);
  xform_kernel<<<512, 256, 0, stream>>>(x, xt);
  convA_mfma_kernel<<<1024, 256, 0, stream>>>(xt, wbtA, off_b, mod_b, offo, masko);
  deform_mfma_kernel<<<2048, 256, 0, stream>>>(xt, offo, masko, wbtB, b, out);
  stats2_kernel<<<1024, 256, 0, stream>>>(out, stat);
  bnrelu_kernel<<<8192, 256, 0, stream>>>(out, stat, gamma, beta);
}

// Round 6
// 230.080 us; speedup vs baseline: 1.1103x; 1.0846x over previous
//
#include <hip/hip_runtime.h>
#include <math.h>

// Problem constants: B=8, C=64 (in), OC=64 (out), H=W=128, K=3x3=9, PAD=1.
#define Hn 128
#define Wn 128
#define HW 16384
#define NPIX 131072
#define EPSv 1e-5f

// ws layout (floats)
#define XT_OFF   0            // x_t bf16 channels-last [b][y][x][c]: 8388608 shorts = 4194304 floats
#define WBTA_OFF 4194304      // 20480 shorts = 10240 floats
#define WBTB_OFF 4204544      // 40960 shorts = 20480 floats
#define STAT_OFF 4225024      // 128 (sum[64], sumsq[64])

// R16 (this round): FUSE convA into deform. Evidence: R13/R14/R15 all tried
// to fix deform's latency-boundness via occupancy/MLP and all landed 96-103
// vs R12's 85.3 (compiler collapses the load window every time). Orthogonal
// deterministic win instead: convA block (b,h) produces exactly the off/mask
// that deform block (b,h) consumes -> compute the 27 channels via MFMA into
// LDS (phase 1), build geometry from LDS (phase 2), run the PROVEN R12
// deform body (phase 3, 85.3us measured). Deletes: one dispatch, 14 MB of
// off/mask writes + 14 MB of reads, and convA's duplicate xt pass (lines
// now L1/L2-hot from phase 1). cvt_pk bf16 packing kept (rode R13-R15).

typedef short s16x8 __attribute__((ext_vector_type(8)));
typedef unsigned short u16x4 __attribute__((ext_vector_type(4)));
typedef float f32x4 __attribute__((ext_vector_type(4)));
typedef unsigned int u32x4 __attribute__((ext_vector_type(4)));

__device__ __forceinline__ unsigned short f2bf(float f) {
  unsigned u = __float_as_uint(f);
  return (unsigned short)((u + 0x7fffu + ((u >> 16) & 1u)) >> 16);  // RNE
}
__device__ __forceinline__ float bf2f(unsigned short s) {
  return __uint_as_float((unsigned)s << 16);
}
__device__ __forceinline__ unsigned cvt_pk_bf16(float lo, float hi) {
  unsigned r;
  asm("v_cvt_pk_bf16_f32 %0, %1, %2" : "=v"(r) : "v"(lo), "v"(hi));
  return r;
}

// ---------------- prep: pack weights into MFMA operand order; zero stat ----------------
__global__ __launch_bounds__(256) void prep_kernel(
    const float* __restrict__ off_w, const float* __restrict__ mod_w,
    const float* __restrict__ w, unsigned short* __restrict__ wbtA,
    unsigned short* __restrict__ wbtB, float* __restrict__ stat) {
  int i = blockIdx.x * 256 + threadIdx.x;
  if (i < 128) stat[i] = 0.f;
  if (i < 20480) {
    // wbtA: A-operand (weights as rows) for phase 1 of the fused kernel.
    int e = i & 31, oc = (i >> 5) & 31, it = i >> 10;
    int tp = it % 5, chunk = it / 5;
    int tap = tp * 2 + (e >> 4);
    int c = (chunk << 4) + (e & 15);
    float v = 0.f;
    if (tap < 9) {
      if (oc < 18) v = off_w[(oc * 64 + c) * 9 + tap];
      else if (oc < 27) v = mod_w[((oc - 18) * 64 + c) * 9 + tap];
    }
    wbtA[i] = f2bf(v);
  } else if (i < 20480 + 40960) {
    // wbtB: B-operand fragments for phase 3 (deform).
    // index = ((it*4 + nt)*64 + lane)*8 + j
    // value = w[oc = nt*16 + (lane&15)][c][tap], where
    //   tap = (it%5)*2 + (lane>>5), c = (it/5)*16 + ((lane>>4)&1)*8 + j
    int j = i - 20480;
    int j3 = j & 7;
    int l = (j >> 3) & 63;
    int nt = (j >> 9) & 3;
    int it = j >> 11;
    int tp = it % 5, chunk = it / 5;
    int tap = tp * 2 + (l >> 5);
    int c = (chunk << 4) + (((l >> 4) & 1) << 3) + j3;
    int oc = (nt << 4) + (l & 15);
    float v = (tap < 9) ? w[(oc * 64 + c) * 9 + tap] : 0.f;
    wbtB[j] = f2bf(v);
  }
}

// ---------------- xform: x (NCHW fp32) -> x_t (NHWC bf16) ----------------
__global__ __launch_bounds__(256) void xform_kernel(
    const float* __restrict__ x, unsigned short* __restrict__ xt) {
  int blk = blockIdx.x;                       // 512 blocks
  int b = blk & 7;
  int hw = ((blk >> 3) << 8) + threadIdx.x;   // 0..16383
  const float* xb = x + ((size_t)(b << 6) << 14) + hw;
  unsigned short* o = xt + (((size_t)(b << 14)) + hw) * 64;
#pragma unroll
  for (int g = 0; g < 8; ++g) {
    float v[8];
#pragma unroll
    for (int j = 0; j < 8; ++j) v[j] = xb[(size_t)((g << 3) + j) << 14];
    s16x8 pk;
#pragma unroll
    for (int j = 0; j < 8; ++j) pk[j] = (short)f2bf(v[j]);
    *(s16x8*)(o + (g << 3)) = pk;
  }
}

// ---------------- fused kernel: convA (->LDS) + geometry + deform MFMA ----------------
__global__ __launch_bounds__(256, 4) void fused_dconv_kernel(
    const unsigned short* __restrict__ xt, const unsigned short* __restrict__ wbtA,
    const unsigned short* __restrict__ wbtB,
    const float* __restrict__ off_b, const float* __restrict__ mod_b,
    const float* __restrict__ bias, float* __restrict__ y) {
  __shared__ float offm[27 * 128];              // 13824 B: off rows 0..17, mask rows 18..26
  __shared__ unsigned short geow[9 * 128 * 4];  // 9216 B: w00,w01,w10,w11 bf16 (mask folded)
  __shared__ unsigned short geoi[9 * 128];      // 2304 B: ibase = rbase*128+cbase
  int t = threadIdx.x;
  int bx = blockIdx.x;                  // 1024 = 8 b x 128 h
  int b = bx & 7, h = bx >> 3;
  int lane = t & 63, wv = t >> 6;
  int ln = lane & 15, quad = (lane >> 4) & 3;
  int hw = h << 7;

  const unsigned short* xtb = xt + ((size_t)(b << 14)) * 64;

  // ===== phase 1: offset+mask conv via MFMA, results to LDS =====
  {
    int p0 = (wv << 5) + ln, p1 = p0 + 16;
    int s_ = quad >> 1, cj = (quad & 1) << 3;
    f32x4 acc[2][2];
#pragma unroll
    for (int mt = 0; mt < 2; ++mt)
#pragma unroll
      for (int nt = 0; nt < 2; ++nt) acc[mt][nt] = (f32x4){0.f, 0.f, 0.f, 0.f};

#pragma unroll 5
    for (int it = 0; it < 20; ++it) {
      int chunk = it / 5, tp = it - chunk * 5;
      int tap = tp * 2 + s_;
      s16x8 B0 = (s16x8){0, 0, 0, 0, 0, 0, 0, 0};
      s16x8 B1 = (s16x8){0, 0, 0, 0, 0, 0, 0, 0};
      if (tap < 9) {
        int gy = h + tap / 3 - 1;
        if (gy >= 0 && gy < Hn) {
          const unsigned short* rowp = xtb + ((size_t)(gy << 7)) * 64 + (chunk << 4) + cj;
          int gx0 = p0 + tap % 3 - 1;
          int gx1 = p1 + tap % 3 - 1;
          if (gx0 >= 0 && gx0 < Wn) B0 = *(const s16x8*)(rowp + (gx0 << 6));
          if (gx1 >= 0 && gx1 < Wn) B1 = *(const s16x8*)(rowp + (gx1 << 6));
        }
      }
#pragma unroll
      for (int mt = 0; mt < 2; ++mt) {
        s16x8 A = *(const s16x8*)(wbtA + (size_t)((it << 5) + (mt << 4) + ln) * 32 + (quad << 3));
        acc[mt][0] = __builtin_amdgcn_mfma_f32_16x16x32_bf16(A, B0, acc[mt][0], 0, 0, 0);
        acc[mt][1] = __builtin_amdgcn_mfma_f32_16x16x32_bf16(A, B1, acc[mt][1], 0, 0, 0);
      }
    }

#pragma unroll
    for (int mt = 0; mt < 2; ++mt)
#pragma unroll
      for (int r = 0; r < 4; ++r) {
        int oc = (mt << 4) + (quad << 2) + r;
#pragma unroll
        for (int nt = 0; nt < 2; ++nt) {
          int px = (wv << 5) + (nt << 4) + ln;
          float val = acc[mt][nt][r];
          if (oc < 18) {
            offm[(oc << 7) + px] = val + off_b[oc];
          } else if (oc < 27) {
            float z = val + mod_b[oc - 18];
            offm[(oc << 7) + px] = 2.f / (1.f + expf(-z));
          }
        }
      }
  }
  __syncthreads();

  // ===== phase 2: geometry for 128 px x 9 taps from LDS =====
  for (int i = t; i < 1152; i += 256) {
    int tap = i >> 7, p2 = i & 127;
    float dy = offm[((2 * tap) << 7) + p2];
    float dx = offm[((2 * tap + 1) << 7) + p2];
    float m = offm[((18 + tap) << 7) + p2];
    float py = dy + (float)(h + tap / 3 - 1);
    float pxf = dx + (float)(p2 + tap % 3 - 1);
    float y0f = floorf(py), x0f = floorf(pxf);
    float ly = py - y0f, lx = pxf - x0f;
    int y0 = (int)y0f, x0 = (int)x0f;
    int y1 = y0 + 1, x1 = x0 + 1;
    float fy0 = (y0 >= 0 && y0 < Hn) ? 1.f : 0.f;
    float fy1 = (y1 >= 0 && y1 < Hn) ? 1.f : 0.f;
    float fx0 = (x0 >= 0 && x0 < Wn) ? 1.f : 0.f;
    float fx1 = (x1 >= 0 && x1 < Wn) ? 1.f : 0.f;
    float ax0 = (1.f - lx) * fx0, ax1 = lx * fx1;
    float ay0 = (1.f - ly) * fy0 * m, ay1 = ly * fy1 * m;
    int cy0 = min(max(y0, 0), Hn - 1), cy1 = min(max(y1, 0), Hn - 1);
    int cx0 = min(max(x0, 0), Wn - 1), cx1 = min(max(x1, 0), Wn - 1);
    int cbase = min(cx0, Wn - 2), rbase = min(cy0, Hn - 2);
    float gx0 = (cx0 == cbase ? ax0 : 0.f) + (cx1 == cbase ? ax1 : 0.f);
    float gx1 = (cx0 == cbase + 1 ? ax0 : 0.f) + (cx1 == cbase + 1 ? ax1 : 0.f);
    float gy0 = (cy0 == rbase ? ay0 : 0.f) + (cy1 == rbase ? ay1 : 0.f);
    float gy1 = (cy0 == rbase + 1 ? ay0 : 0.f) + (cy1 == rbase + 1 ? ay1 : 0.f);
    unsigned short* gw = geow + i * 4;
    gw[0] = f2bf(gy0 * gx0);
    gw[1] = f2bf(gy0 * gx1);
    gw[2] = f2bf(gy1 * gx0);
    gw[3] = f2bf(gy1 * gx1);
    geoi[i] = (unsigned short)((rbase << 7) + cbase);
  }
  __syncthreads();

  // ===== phase 3: deform MFMA (verbatim R12 structure, 85.3us measured) =====
  int l4 = ln;
  int s4 = lane >> 4;        // k-slice 0..3
  int tapS = lane >> 5;      // which tap of the pair
  int chalf = s4 & 1;        // which 8ch half of the 16ch chunk

  f32x4 acc[2][4];  // [m-tile (px 16)][n-tile (oc 16)]
#pragma unroll
  for (int m = 0; m < 2; ++m)
#pragma unroll
    for (int n = 0; n < 4; ++n) acc[m][n] = (f32x4){0.f, 0.f, 0.f, 0.f};

  for (int tp = 0; tp < 5; ++tp) {
    int tap = tp * 2 + tapS;
    bool live = (tap < 9);
    float w00[2], w01[2], w10[2], w11[2];
    const unsigned short* cpb[2];
#pragma unroll
    for (int m = 0; m < 2; ++m) {
      if (live) {
        int px = (wv << 5) + (m << 4) + l4;
        int gidx = (tap << 7) + px;
        u16x4 wq = *(const u16x4*)(geow + gidx * 4);
        unsigned ib = geoi[gidx];
        w00[m] = bf2f(wq[0]);
        w01[m] = bf2f(wq[1]);
        w10[m] = bf2f(wq[2]);
        w11[m] = bf2f(wq[3]);
        cpb[m] = xtb + (size_t)ib * 64 + (chalf << 3);
      } else {
        cpb[m] = xtb;
        w00[m] = w01[m] = w10[m] = w11[m] = 0.f;
      }
    }
#pragma unroll 2
    for (int chunk = 0; chunk < 4; ++chunk) {
      int it = chunk * 5 + tp;
      s16x8 A[2];
#pragma unroll
      for (int m = 0; m < 2; ++m) {
        if (live) {
          const unsigned short* cp = cpb[m] + (chunk << 4);
          s16x8 c00 = *(const s16x8*)(cp);
          s16x8 c01 = *(const s16x8*)(cp + 64);
          s16x8 c10 = *(const s16x8*)(cp + 8192);
          s16x8 c11 = *(const s16x8*)(cp + 8192 + 64);
          u32x4 au;
#pragma unroll
          for (int jj = 0; jj < 4; ++jj) {
            float v0 = w00[m] * bf2f((unsigned short)c00[2 * jj]) +
                       w01[m] * bf2f((unsigned short)c01[2 * jj]) +
                       w10[m] * bf2f((unsigned short)c10[2 * jj]) +
                       w11[m] * bf2f((unsigned short)c11[2 * jj]);
            float v1 = w00[m] * bf2f((unsigned short)c00[2 * jj + 1]) +
                       w01[m] * bf2f((unsigned short)c01[2 * jj + 1]) +
                       w10[m] * bf2f((unsigned short)c10[2 * jj + 1]) +
                       w11[m] * bf2f((unsigned short)c11[2 * jj + 1]);
            au[jj] = cvt_pk_bf16(v0, v1);
          }
          A[m] = __builtin_bit_cast(s16x8, au);
        } else {
          A[m] = (s16x8){0, 0, 0, 0, 0, 0, 0, 0};
        }
      }
      const unsigned short* wb = wbtB + (((size_t)it) << 11) + (lane << 3);
#pragma unroll
      for (int n = 0; n < 4; ++n) {
        s16x8 Bf = *(const s16x8*)(wb + (n << 9));
        acc[0][n] = __builtin_amdgcn_mfma_f32_16x16x32_bf16(A[0], Bf, acc[0][n], 0, 0, 0);
        acc[1][n] = __builtin_amdgcn_mfma_f32_16x16x32_bf16(A[1], Bf, acc[1][n], 0, 0, 0);
      }
    }
  }

  // epilogue: D row = px-in-tile = s4*4+r (float4 over r), col = oc-in-tile = l4
#pragma unroll
  for (int m = 0; m < 2; ++m) {
    int px0 = (wv << 5) + (m << 4) + (s4 << 2);
#pragma unroll
    for (int n = 0; n < 4; ++n) {
      int oc = (n << 4) + l4;
      float bv = bias[oc];
      float4 o;
      o.x = acc[m][n][0] + bv;
      o.y = acc[m][n][1] + bv;
      o.z = acc[m][n][2] + bv;
      o.w = acc[m][n][3] + bv;
      *(float4*)(y + (((size_t)(b << 6) + oc) << 14) + hw + px0) = o;
    }
  }
}

// ---------------- kernel C: per-channel sum/sumsq (sliced, atomics into stat) ----------------
__global__ __launch_bounds__(256) void stats2_kernel(
    const float* __restrict__ y, float* __restrict__ stat) {
  int bxx = blockIdx.x;            // 1024 = 64 ch x 16 slices
  int c = bxx & 63, sl = bxx >> 6;
  int bb = sl >> 1;
  const float4* yp = (const float4*)(y + (((size_t)bb * 64 + c) << 14) + ((sl & 1) << 13));
  float s = 0.f, ss = 0.f;
  for (int i = threadIdx.x; i < 2048; i += 256) {
    float4 v = yp[i];
    s += v.x + v.y + v.z + v.w;
    ss += v.x * v.x + v.y * v.y + v.z * v.z + v.w * v.w;
  }
#pragma unroll
  for (int o = 32; o > 0; o >>= 1) {
    s += __shfl_xor(s, o);
    ss += __shfl_xor(ss, o);
  }
  __shared__ float shs[4], shss[4];
  int lane = threadIdx.x & 63, wv = threadIdx.x >> 6;
  if (lane == 0) { shs[wv] = s; shss[wv] = ss; }
  __syncthreads();
  if (threadIdx.x == 0) {
    float S = shs[0] + shs[1] + shs[2] + shs[3];
    float SS = shss[0] + shss[1] + shss[2] + shss[3];
    atomicAdd(stat + c, S);
    atomicAdd(stat + 64 + c, SS);
  }
}

// ---------------- kernel D: batchnorm scale/shift + relu, in place ----------------
__global__ __launch_bounds__(256) void bnrelu_kernel(
    float* __restrict__ y, const float* __restrict__ stat,
    const float* __restrict__ gamma, const float* __restrict__ beta) {
  float4* y4 = (float4*)y;
  for (int i = blockIdx.x * 256 + threadIdx.x; i < 2097152; i += gridDim.x * 256) {
    int c = (i >> 12) & 63;
    float mean = stat[c] * (1.f / (float)NPIX);
    float var = stat[64 + c] * (1.f / (float)NPIX) - mean * mean;
    float r = rsqrtf(var + EPSv);
    float g = gamma[c] * r;
    float bt = beta[c] - mean * g;
    float4 v = y4[i];
    v.x = fmaxf(v.x * g + bt, 0.f);
    v.y = fmaxf(v.y * g + bt, 0.f);
    v.z = fmaxf(v.z * g + bt, 0.f);
    v.w = fmaxf(v.w * g + bt, 0.f);
    y4[i] = v;
  }
}

extern "C" void kernel_launch(void* const* d_in, const int* in_sizes, int n_in,
                              void* d_out, int out_size, void* d_ws, size_t ws_size,
                              hipStream_t stream) {
  const float* x     = (const float*)d_in[0];
  const float* off_w = (const float*)d_in[1];
  const float* off_b = (const float*)d_in[2];
  const float* mod_w = (const float*)d_in[3];
  const float* mod_b = (const float*)d_in[4];
  const float* w     = (const float*)d_in[5];
  const float* b     = (const float*)d_in[6];
  const float* gamma = (const float*)d_in[7];
  const float* beta  = (const float*)d_in[8];
  float* out = (float*)d_out;
  float* ws  = (float*)d_ws;

  unsigned short* xt  = (unsigned short*)(ws + XT_OFF);
  unsigned short* wbtA = (unsigned short*)(ws + WBTA_OFF);
  unsigned short* wbtB = (unsigned short*)(ws + WBTB_OFF);
  float* stat  = ws + STAT_OFF;

  prep_kernel<<<240, 256, 0, stream>>>(off_w, mod_w, w, wbtA, wbtB, stat);
  xform_kernel<<<512, 256, 0, stream>>>(x, xt);
  fused_dconv_kernel<<<1024, 256, 0, stream>>>(xt, wbtA, wbtB, off_b, mod_b, b, out);
  stats2_kernel<<<1024, 256, 0, stream>>>(out, stat);
  bnrelu_kernel<<<8192, 256, 0, stream>>>(out, stat, gamma, beta);
}